// Round 1
// baseline (822.435 us; speedup 1.0000x reference)
//
#include <hip/hip_runtime.h>
#include <math.h>

#define HDIM 128
#define G4 512  // 4*H

__device__ __forceinline__ float sigm(float v) { return 1.0f / (1.0f + __expf(-v)); }
__device__ __forceinline__ float ftanh(float v) {
    // tanh(x) = 1 - 2/(exp(2x)+1); saturates correctly at +/-inf
    return 1.0f - 2.0f / (__expf(2.0f * v) + 1.0f);
}

// ---- prep: Wc[512][256] = [W_ih[:, :128] + W_hh | W_ih[:, 128:256]], bias = b_ih + b_hh
__global__ void k_prep(const float* __restrict__ W_ih, const float* __restrict__ W_hh,
                       const float* __restrict__ b_ih, const float* __restrict__ b_hh,
                       float* __restrict__ Wc, float* __restrict__ bias) {
    int idx = blockIdx.x * blockDim.x + threadIdx.x;
    if (idx < G4 * 2 * HDIM) {
        int g = idx >> 8;   // /256
        int k = idx & 255;
        float w = W_ih[g * 256 + k];
        if (k < HDIM) w += W_hh[g * HDIM + k];
        Wc[idx] = w;
    }
    if (idx < G4) bias[idx] = b_ih[idx] + b_hh[idx];
}

// ---- segment starts via binary search (batch_vec sorted ascending)
__global__ void k_segstart(const int* __restrict__ batch_vec, int N, int B,
                           int* __restrict__ seg_start) {
    int b = blockIdx.x * blockDim.x + threadIdx.x;
    if (b > B) return;
    int lo = 0, hi = N;
    while (lo < hi) {
        int mid = (lo + hi) >> 1;
        if (batch_vec[mid] < b) lo = mid + 1; else hi = mid;
    }
    seg_start[b] = lo;
}

// ---- step 0 LSTM: q_star=0, h=0, c=0 -> gates = bias (same for every row)
__global__ void k_lstm0(const float* __restrict__ bias, float* __restrict__ h,
                        float* __restrict__ c, int BH) {
    int idx = blockIdx.x * blockDim.x + threadIdx.x;
    if (idx >= BH) return;
    int hid = idx & (HDIM - 1);
    float gi = bias[hid];
    float gg = bias[2 * HDIM + hid];
    float go = bias[3 * HDIM + hid];
    float cv = sigm(gi) * ftanh(gg);   // sigmoid(f)*c_prev = 0
    c[idx] = cv;
    h[idx] = sigm(go) * ftanh(cv);
}

// ---- fused attention: one wave per segment, online softmax, single pass over x
#define ONLINE_UPD(pv, xv)                                           \
    {                                                                \
        float mn_ = fmaxf(m, (pv));                                  \
        float sc_ = __expf(m - mn_);                                 \
        float pe_ = __expf((pv) - mn_);                              \
        denom = denom * sc_ + pe_;                                   \
        rx = rx * sc_ + pe_ * (xv).x;                                \
        ry = ry * sc_ + pe_ * (xv).y;                                \
        m = mn_;                                                     \
    }

__global__ __launch_bounds__(256) void k_attn(const float* __restrict__ x,
                                              const float* __restrict__ q,
                                              const int* __restrict__ seg_start,
                                              float* __restrict__ r_out, int ldr, int col_off,
                                              int B) {
    int wave = threadIdx.x >> 6;
    int lane = threadIdx.x & 63;
    int seg = (blockIdx.x << 2) + wave;
    if (seg >= B) return;
    int s = seg_start[seg];
    int e = seg_start[seg + 1];
    float2 qv = *(const float2*)(q + (size_t)seg * HDIM + lane * 2);
    float m = -INFINITY, denom = 0.0f, rx = 0.0f, ry = 0.0f;
    int n = s;
    for (; n + 4 <= e; n += 4) {
        float2 x0 = *(const float2*)(x + (size_t)(n + 0) * HDIM + lane * 2);
        float2 x1 = *(const float2*)(x + (size_t)(n + 1) * HDIM + lane * 2);
        float2 x2 = *(const float2*)(x + (size_t)(n + 2) * HDIM + lane * 2);
        float2 x3 = *(const float2*)(x + (size_t)(n + 3) * HDIM + lane * 2);
        float p0 = x0.x * qv.x + x0.y * qv.y;
        float p1 = x1.x * qv.x + x1.y * qv.y;
        float p2 = x2.x * qv.x + x2.y * qv.y;
        float p3 = x3.x * qv.x + x3.y * qv.y;
#pragma unroll
        for (int off = 32; off > 0; off >>= 1) {
            p0 += __shfl_xor(p0, off, 64);
            p1 += __shfl_xor(p1, off, 64);
            p2 += __shfl_xor(p2, off, 64);
            p3 += __shfl_xor(p3, off, 64);
        }
        ONLINE_UPD(p0, x0)
        ONLINE_UPD(p1, x1)
        ONLINE_UPD(p2, x2)
        ONLINE_UPD(p3, x3)
    }
    for (; n < e; ++n) {
        float2 xv = *(const float2*)(x + (size_t)n * HDIM + lane * 2);
        float p = xv.x * qv.x + xv.y * qv.y;
#pragma unroll
        for (int off = 32; off > 0; off >>= 1) p += __shfl_xor(p, off, 64);
        ONLINE_UPD(p, xv)
    }
    float inv = (denom > 0.0f) ? 1.0f / denom : 0.0f;
    float2 out;
    out.x = rx * inv;
    out.y = ry * inv;
    *(float2*)(r_out + (size_t)seg * ldr + col_off + lane * 2) = out;
}

// ---- fused GEMM + LSTM cell.
// gates[b][g] = sum_k A[b][k] * Wc[g][k], A = [h_prev | r_prev], K = 256.
// Block tile: 64 batch rows x 128 gate-cols, where the 128 cols are
// { ct*32 + c + 128*qgate : c in [0,32), qgate in [0,4) } -> epilogue has all 4 gates.
__global__ __launch_bounds__(256) void k_gemm_lstm(const float* __restrict__ h_prev,
                                                   const float* __restrict__ r_prev,
                                                   const float* __restrict__ c_prev,
                                                   const float* __restrict__ Wc,
                                                   const float* __restrict__ bias,
                                                   float* __restrict__ h_new,
                                                   float* __restrict__ c_new,
                                                   float* __restrict__ h_mirror) {
    __shared__ float As[64][68];
    __shared__ float Ws[128][68];
    int ct = blockIdx.y;           // col tile: hidx base ct*32
    int rb = blockIdx.x * 64;      // batch row base
    int tid = threadIdx.x;
    int tx = tid & 15, ty = tid >> 4;
    float acc[4][8];
#pragma unroll
    for (int i = 0; i < 4; ++i)
#pragma unroll
        for (int j = 0; j < 8; ++j) acc[i][j] = 0.0f;

    for (int kc = 0; kc < 4; ++kc) {  // K chunks of 64
        const float* src = (kc < 2) ? h_prev : r_prev;
        int kbase = (kc & 1) * 64;
        // stage A: 64 rows x 64 k
#pragma unroll
        for (int i = 0; i < 4; ++i) {
            int li = tid + i * 256;           // [0,1024)
            int row = li >> 4;
            int c4 = (li & 15) * 4;
            float4 v = *(const float4*)(src + (size_t)(rb + row) * HDIM + kbase + c4);
            *(float4*)&As[row][c4] = v;
        }
        // stage W: 128 cols x 64 k
#pragma unroll
        for (int i = 0; i < 8; ++i) {
            int li = tid + i * 256;           // [0,2048)
            int col = li >> 4;
            int c4 = (li & 15) * 4;
            int g = ct * 32 + (col & 31) + 128 * (col >> 5);
            float4 v = *(const float4*)(Wc + (size_t)g * 256 + kc * 64 + c4);
            *(float4*)&Ws[col][c4] = v;
        }
        __syncthreads();
#pragma unroll
        for (int k = 0; k < 64; k += 4) {
            float4 a[4], b[8];
#pragma unroll
            for (int i = 0; i < 4; ++i) a[i] = *(float4*)&As[ty * 4 + i][k];
#pragma unroll
            for (int j = 0; j < 8; ++j) b[j] = *(float4*)&Ws[tx + j * 16][k];
#pragma unroll
            for (int i = 0; i < 4; ++i)
#pragma unroll
                for (int j = 0; j < 8; ++j) {
                    acc[i][j] += a[i].x * b[j].x + a[i].y * b[j].y +
                                 a[i].z * b[j].z + a[i].w * b[j].w;
                }
        }
        __syncthreads();
    }
    // epilogue: thread (tx,ty) holds, for rows ty*4+i, cols tx+j*16:
    // gate q = j/2, hidx = ct*32 + tx + (j%2)*16  -> all 4 gates present per (row,hidx)
#pragma unroll
    for (int jj = 0; jj < 2; ++jj) {
        int hidx = ct * 32 + tx + jj * 16;
        float bi = bias[hidx];
        float bf = bias[HDIM + hidx];
        float bg = bias[2 * HDIM + hidx];
        float bo = bias[3 * HDIM + hidx];
#pragma unroll
        for (int i = 0; i < 4; ++i) {
            int row = rb + ty * 4 + i;
            float gi = acc[i][0 + jj] + bi;
            float gf = acc[i][2 + jj] + bf;
            float gg = acc[i][4 + jj] + bg;
            float go = acc[i][6 + jj] + bo;
            float cp = c_prev[(size_t)row * HDIM + hidx];
            float cn = sigm(gf) * cp + sigm(gi) * ftanh(gg);
            float hn = sigm(go) * ftanh(cn);
            c_new[(size_t)row * HDIM + hidx] = cn;
            h_new[(size_t)row * HDIM + hidx] = hn;
            if (h_mirror) h_mirror[(size_t)row * 2 * HDIM + hidx] = hn;
        }
    }
}

extern "C" void kernel_launch(void* const* d_in, const int* in_sizes, int n_in,
                              void* d_out, int out_size, void* d_ws, size_t ws_size,
                              hipStream_t stream) {
    const float* x = (const float*)d_in[0];
    const int* batch_vec = (const int*)d_in[1];
    const float* W_ih = (const float*)d_in[2];
    const float* W_hh = (const float*)d_in[3];
    const float* b_ih = (const float*)d_in[4];
    const float* b_hh = (const float*)d_in[5];
    float* out = (float*)d_out;

    int N = in_sizes[1];            // 1,000,000
    int B = out_size / (2 * HDIM);  // 16384

    char* ws = (char*)d_ws;
    float* Wc = (float*)ws;   ws += (size_t)G4 * 2 * HDIM * 4;
    float* bias = (float*)ws; ws += (size_t)G4 * 4;
    float* h_a = (float*)ws;  ws += (size_t)B * HDIM * 4;
    float* h_b = (float*)ws;  ws += (size_t)B * HDIM * 4;
    float* cbuf = (float*)ws; ws += (size_t)B * HDIM * 4;
    float* rbuf = (float*)ws; ws += (size_t)B * HDIM * 4;
    int* seg = (int*)ws;      ws += (size_t)(B + 1) * 4;

    k_prep<<<(G4 * 2 * HDIM + 255) / 256, 256, 0, stream>>>(W_ih, W_hh, b_ih, b_hh, Wc, bias);
    k_segstart<<<(B + 1 + 255) / 256, 256, 0, stream>>>(batch_vec, N, B, seg);

    // step 0: gates = bias
    k_lstm0<<<(B * HDIM + 255) / 256, 256, 0, stream>>>(bias, h_a, cbuf, B * HDIM);
    k_attn<<<(B + 3) / 4, 256, 0, stream>>>(x, h_a, seg, rbuf, HDIM, 0, B);

    dim3 ggrid(B / 64, 4);
    // step 1
    k_gemm_lstm<<<ggrid, 256, 0, stream>>>(h_a, rbuf, cbuf, Wc, bias, h_b, cbuf, nullptr);
    k_attn<<<(B + 3) / 4, 256, 0, stream>>>(x, h_b, seg, rbuf, HDIM, 0, B);
    // step 2: h goes to out[:, :128] (mirror), r goes to out[:, 128:256]
    k_gemm_lstm<<<ggrid, 256, 0, stream>>>(h_b, rbuf, cbuf, Wc, bias, h_a, cbuf, out);
    k_attn<<<(B + 3) / 4, 256, 0, stream>>>(x, h_a, seg, out, 2 * HDIM, HDIM, B);
}

// Round 2
// 813.900 us; speedup vs baseline: 1.0105x; 1.0105x over previous
//
#include <hip/hip_runtime.h>
#include <math.h>

#define HDIM 128
#define G4 512  // 4*H

__device__ __forceinline__ float sigm(float v) { return 1.0f / (1.0f + __expf(-v)); }
__device__ __forceinline__ float ftanh(float v) {
    return 1.0f - 2.0f / (__expf(2.0f * v) + 1.0f);
}

// ---- prep: Wc[512][256] = [W_ih[:, :128] + W_hh | W_ih[:, 128:256]], bias = b_ih + b_hh
__global__ void k_prep(const float* __restrict__ W_ih, const float* __restrict__ W_hh,
                       const float* __restrict__ b_ih, const float* __restrict__ b_hh,
                       float* __restrict__ Wc, float* __restrict__ bias) {
    int idx = blockIdx.x * blockDim.x + threadIdx.x;
    if (idx < G4 * 2 * HDIM) {
        int g = idx >> 8;   // /256
        int k = idx & 255;
        float w = W_ih[g * 256 + k];
        if (k < HDIM) w += W_hh[g * HDIM + k];
        Wc[idx] = w;
    }
    if (idx < G4) bias[idx] = b_ih[idx] + b_hh[idx];
}

// ---- segment starts via binary search (batch_vec sorted ascending)
__global__ void k_segstart(const int* __restrict__ batch_vec, int N, int B,
                           int* __restrict__ seg_start) {
    int b = blockIdx.x * blockDim.x + threadIdx.x;
    if (b > B) return;
    int lo = 0, hi = N;
    while (lo < hi) {
        int mid = (lo + hi) >> 1;
        if (batch_vec[mid] < b) lo = mid + 1; else hi = mid;
    }
    seg_start[b] = lo;
}

// ---- step 0 LSTM: q_star=0, h=0, c=0 -> gates = bias
__global__ void k_lstm0(const float* __restrict__ bias, float* __restrict__ h,
                        float* __restrict__ c, int BH) {
    int idx = blockIdx.x * blockDim.x + threadIdx.x;
    if (idx >= BH) return;
    int hid = idx & (HDIM - 1);
    float gi = bias[hid];
    float gg = bias[2 * HDIM + hid];
    float go = bias[3 * HDIM + hid];
    float cv = sigm(gi) * ftanh(gg);
    c[idx] = cv;
    h[idx] = sigm(go) * ftanh(cv);
}

// ---- fused attention: one wave per segment, 16 lanes/row x 4 rows/wave,
// online softmax with 4 independent quarter-states merged at the end.
__global__ __launch_bounds__(256) void k_attn(const float* __restrict__ x,
                                              const float* __restrict__ q,
                                              const int* __restrict__ seg_start,
                                              float* __restrict__ r_out, int ldr, int col_off,
                                              int B) {
    int wave = threadIdx.x >> 6;
    int lane = threadIdx.x & 63;
    int l16 = lane & 15;
    int quarter = lane >> 4;
    int seg = (blockIdx.x << 2) + wave;
    if (seg >= B) return;
    int s = seg_start[seg];
    int e = seg_start[seg + 1];

    const float* qrow = q + (size_t)seg * HDIM;
    float4 qa = *(const float4*)(qrow + l16 * 4);
    float4 qb = *(const float4*)(qrow + 64 + l16 * 4);

    float m = 0.0f, denom = 0.0f;
    float4 ra = {0.f, 0.f, 0.f, 0.f}, rb = {0.f, 0.f, 0.f, 0.f};

    int base = s;
#pragma unroll 2
    for (; base + 4 <= e; base += 4) {
        const float* xr = x + (size_t)(base + quarter) * HDIM;
        float4 xa = *(const float4*)(xr + l16 * 4);
        float4 xb = *(const float4*)(xr + 64 + l16 * 4);
        float p = xa.x * qa.x + xa.y * qa.y + xa.z * qa.z + xa.w * qa.w +
                  xb.x * qb.x + xb.y * qb.y + xb.z * qb.z + xb.w * qb.w;
        p += __shfl_xor(p, 1, 64);
        p += __shfl_xor(p, 2, 64);
        p += __shfl_xor(p, 4, 64);
        p += __shfl_xor(p, 8, 64);
        float mn = fmaxf(m, p);
        float sc = __expf(m - mn);
        float pe = __expf(p - mn);
        denom = denom * sc + pe;
        ra.x = ra.x * sc + pe * xa.x;
        ra.y = ra.y * sc + pe * xa.y;
        ra.z = ra.z * sc + pe * xa.z;
        ra.w = ra.w * sc + pe * xa.w;
        rb.x = rb.x * sc + pe * xb.x;
        rb.y = rb.y * sc + pe * xb.y;
        rb.z = rb.z * sc + pe * xb.z;
        rb.w = rb.w * sc + pe * xb.w;
        m = mn;
    }
    if (base < e) {  // tail: 1..3 rows
        int row = base + quarter;
        int rl = min(row, e - 1);
        const float* xr = x + (size_t)rl * HDIM;
        float4 xa = *(const float4*)(xr + l16 * 4);
        float4 xb = *(const float4*)(xr + 64 + l16 * 4);
        float p = xa.x * qa.x + xa.y * qa.y + xa.z * qa.z + xa.w * qa.w +
                  xb.x * qb.x + xb.y * qb.y + xb.z * qb.z + xb.w * qb.w;
        p += __shfl_xor(p, 1, 64);
        p += __shfl_xor(p, 2, 64);
        p += __shfl_xor(p, 4, 64);
        p += __shfl_xor(p, 8, 64);
        if (row >= e) p = -1e30f;
        float mn = fmaxf(m, p);
        float sc = __expf(m - mn);
        float pe = __expf(p - mn);
        denom = denom * sc + pe;
        ra.x = ra.x * sc + pe * xa.x;
        ra.y = ra.y * sc + pe * xa.y;
        ra.z = ra.z * sc + pe * xa.z;
        ra.w = ra.w * sc + pe * xa.w;
        rb.x = rb.x * sc + pe * xb.x;
        rb.y = rb.y * sc + pe * xb.y;
        rb.z = rb.z * sc + pe * xb.z;
        rb.w = rb.w * sc + pe * xb.w;
        m = mn;
    }
    // merge the 4 quarter-states: xor 16, then xor 32
#pragma unroll
    for (int off = 16; off <= 32; off <<= 1) {
        float om = __shfl_xor(m, off, 64);
        float M = fmaxf(m, om);
        float w = __expf(m - M);
        denom *= w;
        ra.x *= w; ra.y *= w; ra.z *= w; ra.w *= w;
        rb.x *= w; rb.y *= w; rb.z *= w; rb.w *= w;
        denom += __shfl_xor(denom, off, 64);
        ra.x += __shfl_xor(ra.x, off, 64);
        ra.y += __shfl_xor(ra.y, off, 64);
        ra.z += __shfl_xor(ra.z, off, 64);
        ra.w += __shfl_xor(ra.w, off, 64);
        rb.x += __shfl_xor(rb.x, off, 64);
        rb.y += __shfl_xor(rb.y, off, 64);
        rb.z += __shfl_xor(rb.z, off, 64);
        rb.w += __shfl_xor(rb.w, off, 64);
        m = M;
    }
    float inv = (denom > 0.0f) ? 1.0f / denom : 0.0f;
    float* dst = r_out + (size_t)seg * ldr + col_off;
    if (quarter == 0) {
        float4 o;
        o.x = ra.x * inv; o.y = ra.y * inv; o.z = ra.z * inv; o.w = ra.w * inv;
        *(float4*)(dst + l16 * 4) = o;
    } else if (quarter == 1) {
        float4 o;
        o.x = rb.x * inv; o.y = rb.y * inv; o.z = rb.z * inv; o.w = rb.w * inv;
        *(float4*)(dst + 64 + l16 * 4) = o;
    }
}

// ---- fused GEMM + LSTM cell (unchanged from R0).
__global__ __launch_bounds__(256) void k_gemm_lstm(const float* __restrict__ h_prev,
                                                   const float* __restrict__ r_prev,
                                                   const float* __restrict__ c_prev,
                                                   const float* __restrict__ Wc,
                                                   const float* __restrict__ bias,
                                                   float* __restrict__ h_new,
                                                   float* __restrict__ c_new,
                                                   float* __restrict__ h_mirror) {
    __shared__ float As[64][68];
    __shared__ float Ws[128][68];
    int ct = blockIdx.y;
    int rb = blockIdx.x * 64;
    int tid = threadIdx.x;
    int tx = tid & 15, ty = tid >> 4;
    float acc[4][8];
#pragma unroll
    for (int i = 0; i < 4; ++i)
#pragma unroll
        for (int j = 0; j < 8; ++j) acc[i][j] = 0.0f;

    for (int kc = 0; kc < 4; ++kc) {
        const float* src = (kc < 2) ? h_prev : r_prev;
        int kbase = (kc & 1) * 64;
#pragma unroll
        for (int i = 0; i < 4; ++i) {
            int li = tid + i * 256;
            int row = li >> 4;
            int c4 = (li & 15) * 4;
            float4 v = *(const float4*)(src + (size_t)(rb + row) * HDIM + kbase + c4);
            *(float4*)&As[row][c4] = v;
        }
#pragma unroll
        for (int i = 0; i < 8; ++i) {
            int li = tid + i * 256;
            int col = li >> 4;
            int c4 = (li & 15) * 4;
            int g = ct * 32 + (col & 31) + 128 * (col >> 5);
            float4 v = *(const float4*)(Wc + (size_t)g * 256 + kc * 64 + c4);
            *(float4*)&Ws[col][c4] = v;
        }
        __syncthreads();
#pragma unroll
        for (int k = 0; k < 64; k += 4) {
            float4 a[4], b[8];
#pragma unroll
            for (int i = 0; i < 4; ++i) a[i] = *(float4*)&As[ty * 4 + i][k];
#pragma unroll
            for (int j = 0; j < 8; ++j) b[j] = *(float4*)&Ws[tx + j * 16][k];
#pragma unroll
            for (int i = 0; i < 4; ++i)
#pragma unroll
                for (int j = 0; j < 8; ++j) {
                    acc[i][j] += a[i].x * b[j].x + a[i].y * b[j].y +
                                 a[i].z * b[j].z + a[i].w * b[j].w;
                }
        }
        __syncthreads();
    }
#pragma unroll
    for (int jj = 0; jj < 2; ++jj) {
        int hidx = ct * 32 + tx + jj * 16;
        float bi = bias[hidx];
        float bf = bias[HDIM + hidx];
        float bg = bias[2 * HDIM + hidx];
        float bo = bias[3 * HDIM + hidx];
#pragma unroll
        for (int i = 0; i < 4; ++i) {
            int row = rb + ty * 4 + i;
            float gi = acc[i][0 + jj] + bi;
            float gf = acc[i][2 + jj] + bf;
            float gg = acc[i][4 + jj] + bg;
            float go = acc[i][6 + jj] + bo;
            float cp = c_prev[(size_t)row * HDIM + hidx];
            float cn = sigm(gf) * cp + sigm(gi) * ftanh(gg);
            float hn = sigm(go) * ftanh(cn);
            c_new[(size_t)row * HDIM + hidx] = cn;
            h_new[(size_t)row * HDIM + hidx] = hn;
            if (h_mirror) h_mirror[(size_t)row * 2 * HDIM + hidx] = hn;
        }
    }
}

extern "C" void kernel_launch(void* const* d_in, const int* in_sizes, int n_in,
                              void* d_out, int out_size, void* d_ws, size_t ws_size,
                              hipStream_t stream) {
    const float* x = (const float*)d_in[0];
    const int* batch_vec = (const int*)d_in[1];
    const float* W_ih = (const float*)d_in[2];
    const float* W_hh = (const float*)d_in[3];
    const float* b_ih = (const float*)d_in[4];
    const float* b_hh = (const float*)d_in[5];
    float* out = (float*)d_out;

    int N = in_sizes[1];
    int B = out_size / (2 * HDIM);

    char* ws = (char*)d_ws;
    float* Wc = (float*)ws;   ws += (size_t)G4 * 2 * HDIM * 4;
    float* bias = (float*)ws; ws += (size_t)G4 * 4;
    float* h_a = (float*)ws;  ws += (size_t)B * HDIM * 4;
    float* h_b = (float*)ws;  ws += (size_t)B * HDIM * 4;
    float* cbuf = (float*)ws; ws += (size_t)B * HDIM * 4;
    float* rbuf = (float*)ws; ws += (size_t)B * HDIM * 4;
    int* seg = (int*)ws;      ws += (size_t)(B + 1) * 4;

    k_prep<<<(G4 * 2 * HDIM + 255) / 256, 256, 0, stream>>>(W_ih, W_hh, b_ih, b_hh, Wc, bias);
    k_segstart<<<(B + 1 + 255) / 256, 256, 0, stream>>>(batch_vec, N, B, seg);

    k_lstm0<<<(B * HDIM + 255) / 256, 256, 0, stream>>>(bias, h_a, cbuf, B * HDIM);
    k_attn<<<(B + 3) / 4, 256, 0, stream>>>(x, h_a, seg, rbuf, HDIM, 0, B);

    dim3 ggrid(B / 64, 4);
    k_gemm_lstm<<<ggrid, 256, 0, stream>>>(h_a, rbuf, cbuf, Wc, bias, h_b, cbuf, nullptr);
    k_attn<<<(B + 3) / 4, 256, 0, stream>>>(x, h_b, seg, rbuf, HDIM, 0, B);
    k_gemm_lstm<<<ggrid, 256, 0, stream>>>(h_b, rbuf, cbuf, Wc, bias, h_a, cbuf, out);
    k_attn<<<(B + 3) / 4, 256, 0, stream>>>(x, h_a, seg, out, 2 * HDIM, HDIM, B);
}

// Round 3
// 568.124 us; speedup vs baseline: 1.4476x; 1.4326x over previous
//
#include <hip/hip_runtime.h>
#include <math.h>

#define HDIM 128
#define G4 512  // 4*H

typedef float vf4 __attribute__((ext_vector_type(4)));

__device__ __forceinline__ float sigm(float v) { return 1.0f / (1.0f + __expf(-v)); }
__device__ __forceinline__ float ftanh(float v) {
    return 1.0f - 2.0f / (__expf(2.0f * v) + 1.0f);
}
__device__ __forceinline__ vf4 ldnt4(const float* p) {
    return __builtin_nontemporal_load((const vf4*)p);
}
__device__ __forceinline__ float dot4(vf4 a, vf4 b) {
    return a.x * b.x + a.y * b.y + a.z * b.z + a.w * b.w;
}

// ---- fused setup: Wc prep + segment starts + step-0 LSTM (gates = bias)
__global__ __launch_bounds__(256) void k_setup(const float* __restrict__ W_ih,
                                               const float* __restrict__ W_hh,
                                               const float* __restrict__ b_ih,
                                               const float* __restrict__ b_hh,
                                               const int* __restrict__ batch_vec, int N, int B,
                                               float* __restrict__ Wc, int* __restrict__ seg_start,
                                               float* __restrict__ h, float* __restrict__ c) {
    int t = blockIdx.x * 256 + threadIdx.x;
    if (t < B * HDIM) {  // step-0 LSTM: h=c=0, gates = b_ih+b_hh
        int hid = t & (HDIM - 1);
        float gi = b_ih[hid] + b_hh[hid];
        float gg = b_ih[2 * HDIM + hid] + b_hh[2 * HDIM + hid];
        float go = b_ih[3 * HDIM + hid] + b_hh[3 * HDIM + hid];
        float cv = sigm(gi) * ftanh(gg);
        c[t] = cv;
        h[t] = sigm(go) * ftanh(cv);
    }
    if (t < G4 * 2 * HDIM) {  // Wc[512][256] = [W_ih[:,:128]+W_hh | W_ih[:,128:]]
        int g = t >> 8;
        int k = t & 255;
        float w = W_ih[g * 256 + k];
        if (k < HDIM) w += W_hh[g * HDIM + k];
        Wc[t] = w;
    }
    if (t <= B) {  // segment starts: lower_bound over sorted batch_vec
        int lo = 0, hi = N;
        while (lo < hi) {
            int mid = (lo + hi) >> 1;
            if (batch_vec[mid] < t) lo = mid + 1; else hi = mid;
        }
        seg_start[t] = lo;
    }
}

// ---- fused attention: one wave/segment, 16 lanes/row x 4 rows, dual online state
#define UPD(m_, d_, ra_, rb_, p_, xa_, xb_)  \
    {                                        \
        float mn_ = fmaxf(m_, p_);           \
        float sc_ = __expf(m_ - mn_);        \
        float pe_ = __expf(p_ - mn_);        \
        d_ = d_ * sc_ + pe_;                 \
        ra_ = ra_ * sc_ + pe_ * xa_;         \
        rb_ = rb_ * sc_ + pe_ * xb_;         \
        m_ = mn_;                            \
    }

__global__ __launch_bounds__(256) void k_attn(const float* __restrict__ x,
                                              const float* __restrict__ q,
                                              const int* __restrict__ seg_start,
                                              float* __restrict__ r_out, int ldr, int col_off,
                                              int B) {
    int wave = threadIdx.x >> 6;
    int lane = threadIdx.x & 63;
    int l16 = lane & 15;
    int quarter = lane >> 4;
    int seg = (blockIdx.x << 2) + wave;
    if (seg >= B) return;
    int s = seg_start[seg];
    int e = seg_start[seg + 1];

    const float* qrow = q + (size_t)seg * HDIM;
    vf4 qa = *(const vf4*)(qrow + l16 * 4);
    vf4 qb = *(const vf4*)(qrow + 64 + l16 * 4);

    float m0 = 0.0f, d0 = 0.0f, m1 = 0.0f, d1 = 0.0f;
    vf4 ra0 = {0.f, 0.f, 0.f, 0.f}, rb0 = {0.f, 0.f, 0.f, 0.f};
    vf4 ra1 = {0.f, 0.f, 0.f, 0.f}, rb1 = {0.f, 0.f, 0.f, 0.f};

    int base = s;
#pragma unroll 2
    for (; base + 8 <= e; base += 8) {
        const float* xr0 = x + (size_t)(base + quarter) * HDIM;
        const float* xr1 = xr0 + 4 * HDIM;
        vf4 xa0 = ldnt4(xr0 + l16 * 4), xb0 = ldnt4(xr0 + 64 + l16 * 4);
        vf4 xa1 = ldnt4(xr1 + l16 * 4), xb1 = ldnt4(xr1 + 64 + l16 * 4);
        float p0 = dot4(xa0, qa) + dot4(xb0, qb);
        float p1 = dot4(xa1, qa) + dot4(xb1, qb);
        p0 += __shfl_xor(p0, 1, 64);  p1 += __shfl_xor(p1, 1, 64);
        p0 += __shfl_xor(p0, 2, 64);  p1 += __shfl_xor(p1, 2, 64);
        p0 += __shfl_xor(p0, 4, 64);  p1 += __shfl_xor(p1, 4, 64);
        p0 += __shfl_xor(p0, 8, 64);  p1 += __shfl_xor(p1, 8, 64);
        UPD(m0, d0, ra0, rb0, p0, xa0, xb0)
        UPD(m1, d1, ra1, rb1, p1, xa1, xb1)
    }
    for (; base < e; base += 4) {  // tail: up to 7 rows in masked 4-row groups
        int row = base + quarter;
        const float* xr = x + (size_t)min(row, e - 1) * HDIM;
        vf4 xa = ldnt4(xr + l16 * 4), xb = ldnt4(xr + 64 + l16 * 4);
        float p = dot4(xa, qa) + dot4(xb, qb);
        p += __shfl_xor(p, 1, 64);
        p += __shfl_xor(p, 2, 64);
        p += __shfl_xor(p, 4, 64);
        p += __shfl_xor(p, 8, 64);
        if (row >= e) p = -1e30f;
        UPD(m0, d0, ra0, rb0, p, xa, xb)
    }
    {  // merge state1 -> state0
        float M = fmaxf(m0, m1);
        float w0 = __expf(m0 - M), w1 = __expf(m1 - M);
        d0 = d0 * w0 + d1 * w1;
        ra0 = ra0 * w0 + ra1 * w1;
        rb0 = rb0 * w0 + rb1 * w1;
        m0 = M;
    }
#pragma unroll
    for (int off = 16; off <= 32; off <<= 1) {  // merge the 4 quarter-states
        float om = __shfl_xor(m0, off, 64);
        float M = fmaxf(m0, om);
        float w = __expf(m0 - M);
        d0 *= w;
        ra0 *= w;
        rb0 *= w;
        d0 += __shfl_xor(d0, off, 64);
        ra0.x += __shfl_xor(ra0.x, off, 64);
        ra0.y += __shfl_xor(ra0.y, off, 64);
        ra0.z += __shfl_xor(ra0.z, off, 64);
        ra0.w += __shfl_xor(ra0.w, off, 64);
        rb0.x += __shfl_xor(rb0.x, off, 64);
        rb0.y += __shfl_xor(rb0.y, off, 64);
        rb0.z += __shfl_xor(rb0.z, off, 64);
        rb0.w += __shfl_xor(rb0.w, off, 64);
        m0 = M;
    }
    float inv = (d0 > 0.0f) ? 1.0f / d0 : 0.0f;
    float* dst = r_out + (size_t)seg * ldr + col_off;
    if (quarter == 0) {
        vf4 o = ra0 * inv;
        *(vf4*)(dst + l16 * 4) = o;
    } else if (quarter == 1) {
        vf4 o = rb0 * inv;
        *(vf4*)(dst + 64 + l16 * 4) = o;
    }
}

// ---- fused GEMM + LSTM cell. 64 rows x 64 gate-cols per block, 256 threads.
// cols = { ct*16 + c + 128*gate : c in [0,16), gate in [0,4) }.
// LDS 33.8 KB -> 4 blocks/CU; grid (B/64, 8) = 8 blocks/CU -> two clean rounds.
__global__ __launch_bounds__(256) void k_gemm_lstm(const float* __restrict__ h_prev,
                                                   const float* __restrict__ r_prev,
                                                   const float* __restrict__ c_prev,
                                                   const float* __restrict__ Wc,
                                                   const float* __restrict__ b_ih,
                                                   const float* __restrict__ b_hh,
                                                   float* __restrict__ h_new,
                                                   float* __restrict__ c_new,
                                                   float* __restrict__ h_mirror) {
    __shared__ float As[64][66];
    __shared__ float Ws[64][66];
    int ct = blockIdx.y;           // hidx base ct*16
    int rb = blockIdx.x * 64;      // batch row base
    int tid = threadIdx.x;
    int tx = tid & 15, ty = tid >> 4;
    float acc[4][4];
#pragma unroll
    for (int i = 0; i < 4; ++i)
#pragma unroll
        for (int j = 0; j < 4; ++j) acc[i][j] = 0.0f;

    for (int kc = 0; kc < 4; ++kc) {  // K chunks of 64: kc 0,1 = h; 2,3 = r
        const float* src = (kc < 2) ? h_prev : r_prev;
        int kbase = (kc & 1) * 64;
#pragma unroll
        for (int i = 0; i < 4; ++i) {  // stage A: 64 rows x 64 k
            int li = tid + i * 256;
            int row = li >> 4;
            int c4 = (li & 15) * 4;
            *(vf4*)&As[row][c4] = *(const vf4*)(src + (size_t)(rb + row) * HDIM + kbase + c4);
        }
#pragma unroll
        for (int i = 0; i < 4; ++i) {  // stage W: 64 cols x 64 k
            int li = tid + i * 256;
            int col = li >> 4;
            int c4 = (li & 15) * 4;
            int g = ct * 16 + (col & 15) + 128 * (col >> 4);
            *(vf4*)&Ws[col][c4] = *(const vf4*)(Wc + (size_t)g * 256 + kc * 64 + c4);
        }
        __syncthreads();
#pragma unroll
        for (int k = 0; k < 64; k += 4) {
            vf4 a[4], b[4];
#pragma unroll
            for (int i = 0; i < 4; ++i) a[i] = *(vf4*)&As[ty * 4 + i][k];
#pragma unroll
            for (int j = 0; j < 4; ++j) b[j] = *(vf4*)&Ws[tx + j * 16][k];
#pragma unroll
            for (int i = 0; i < 4; ++i)
#pragma unroll
                for (int j = 0; j < 4; ++j) {
                    acc[i][j] += a[i].x * b[j].x + a[i].y * b[j].y +
                                 a[i].z * b[j].z + a[i].w * b[j].w;
                }
        }
        __syncthreads();
    }
    // epilogue: thread (tx,ty) owns hidx = ct*16+tx, rows rb+ty*4+i, gates j=0..3 (i,f,g,o)
    int hidx = ct * 16 + tx;
    float bi = b_ih[hidx] + b_hh[hidx];
    float bf = b_ih[HDIM + hidx] + b_hh[HDIM + hidx];
    float bg = b_ih[2 * HDIM + hidx] + b_hh[2 * HDIM + hidx];
    float bo = b_ih[3 * HDIM + hidx] + b_hh[3 * HDIM + hidx];
#pragma unroll
    for (int i = 0; i < 4; ++i) {
        int row = rb + ty * 4 + i;
        float gi = acc[i][0] + bi;
        float gf = acc[i][1] + bf;
        float gg = acc[i][2] + bg;
        float go = acc[i][3] + bo;
        float cp = c_prev[(size_t)row * HDIM + hidx];
        float cn = sigm(gf) * cp + sigm(gi) * ftanh(gg);
        float hn = sigm(go) * ftanh(cn);
        c_new[(size_t)row * HDIM + hidx] = cn;
        h_new[(size_t)row * HDIM + hidx] = hn;
        if (h_mirror) h_mirror[(size_t)row * 2 * HDIM + hidx] = hn;
    }
}

extern "C" void kernel_launch(void* const* d_in, const int* in_sizes, int n_in,
                              void* d_out, int out_size, void* d_ws, size_t ws_size,
                              hipStream_t stream) {
    const float* x = (const float*)d_in[0];
    const int* batch_vec = (const int*)d_in[1];
    const float* W_ih = (const float*)d_in[2];
    const float* W_hh = (const float*)d_in[3];
    const float* b_ih = (const float*)d_in[4];
    const float* b_hh = (const float*)d_in[5];
    float* out = (float*)d_out;

    int N = in_sizes[1];
    int B = out_size / (2 * HDIM);

    char* ws = (char*)d_ws;
    float* Wc = (float*)ws;   ws += (size_t)G4 * 2 * HDIM * 4;
    float* h_a = (float*)ws;  ws += (size_t)B * HDIM * 4;
    float* h_b = (float*)ws;  ws += (size_t)B * HDIM * 4;
    float* cbuf = (float*)ws; ws += (size_t)B * HDIM * 4;
    float* rbuf = (float*)ws; ws += (size_t)B * HDIM * 4;
    int* seg = (int*)ws;      ws += (size_t)(B + 1) * 4;

    int setup_grid = (B * HDIM + 255) / 256;
    k_setup<<<setup_grid, 256, 0, stream>>>(W_ih, W_hh, b_ih, b_hh, batch_vec, N, B,
                                            Wc, seg, h_a, cbuf);

    dim3 ggrid(B / 64, 8);
    k_attn<<<(B + 3) / 4, 256, 0, stream>>>(x, h_a, seg, rbuf, HDIM, 0, B);
    k_gemm_lstm<<<ggrid, 256, 0, stream>>>(h_a, rbuf, cbuf, Wc, b_ih, b_hh, h_b, cbuf, nullptr);
    k_attn<<<(B + 3) / 4, 256, 0, stream>>>(x, h_b, seg, rbuf, HDIM, 0, B);
    k_gemm_lstm<<<ggrid, 256, 0, stream>>>(h_b, rbuf, cbuf, Wc, b_ih, b_hh, h_a, cbuf, out);
    k_attn<<<(B + 3) / 4, 256, 0, stream>>>(x, h_a, seg, out, 2 * HDIM, HDIM, B);
}